// Round 2
// baseline (862.406 us; speedup 1.0000x reference)
//
#include <hip/hip_runtime.h>
#include <hip/hip_bf16.h>
#include <cstdint>

// Problem constants (B,S,E,H) = (4, 2048, 256, 8), fp32 in/out.
#define B_N 4
#define S_N 2048
#define E_N 256
#define H_N 8

typedef float f32x4 __attribute__((ext_vector_type(4)));
typedef short s16x8 __attribute__((ext_vector_type(8)));   // 8 bf16 as shorts (4 VGPR)

static __device__ __forceinline__ f32x4 mfma16(s16x8 a, s16x8 b, f32x4 c) {
  return __builtin_amdgcn_mfma_f32_16x16x32_bf16(a, b, c, 0, 0, 0);
}

// fp32 <-> bf16 (RNE) bit ops (used by pre-kernels where exactness matters).
static __device__ __forceinline__ unsigned short f2bf(float f) {
  union { float f; unsigned int u; } v; v.f = f;
  unsigned int r = v.u + 0x7fffu + ((v.u >> 16) & 1u);
  return (unsigned short)(r >> 16);
}
static __device__ __forceinline__ float bf2f(unsigned short s) {
  union { unsigned int u; float f; } v; v.u = ((unsigned int)s) << 16;
  return v.f;
}
static __device__ __forceinline__ unsigned short f2bf_fast(float f) {
  __hip_bfloat16 h = __float2bfloat16(f);
  return *(unsigned short*)&h;
}

// ---------------------------------------------------------------------------
// Split fp32 -> bf16 hi + bf16 lo  (hi = rne(x), lo = rne(x - hi)); vec x4.
__global__ void k_split(const float* __restrict__ src, unsigned short* __restrict__ hi,
                        unsigned short* __restrict__ lo, int n4) {
  int i = blockIdx.x * blockDim.x + threadIdx.x;
  if (i >= n4) return;
  float4 v = ((const float4*)src)[i];
  float f[4] = {v.x, v.y, v.z, v.w};
  unsigned short hh[4], ll[4];
#pragma unroll
  for (int j = 0; j < 4; j++) {
    hh[j] = f2bf(f[j]);
    ll[j] = f2bf(f[j] - bf2f(hh[j]));
  }
  ushort4 h; h.x = hh[0]; h.y = hh[1]; h.z = hh[2]; h.w = hh[3];
  ushort4 l; l.x = ll[0]; l.y = ll[1]; l.z = ll[2]; l.w = ll[3];
  ((ushort4*)hi)[i] = h;
  ((ushort4*)lo)[i] = l;
}

// ---------------------------------------------------------------------------
// WvT[h][f][e] = bf16(Wv[h][e][f])   (32x32 LDS tile transpose)
__global__ void k_transpose_wv(const float* __restrict__ wv, unsigned short* __restrict__ wvT) {
  __shared__ float t[32][33];
  int h = blockIdx.z;
  int e0 = blockIdx.x * 32, f0 = blockIdx.y * 32;
  int tx = threadIdx.x & 31, ty = threadIdx.x >> 5;
  const float* src = wv + ((size_t)h * E_N + e0) * E_N + f0;
#pragma unroll
  for (int r = ty; r < 32; r += 8) t[r][tx] = src[(size_t)r * E_N + tx];
  __syncthreads();
  unsigned short* dst = wvT + ((size_t)h * E_N + f0) * E_N + e0;
#pragma unroll
  for (int r = ty; r < 32; r += 8) dst[(size_t)r * E_N + tx] = f2bf(t[tx][r]);
}

// ---------------------------------------------------------------------------
// bt-GEMM: C[m,n] = sum_k A[m,k]*B[n,k], 128x128 tile, BK=32, 4 waves.
#define BKP 40  // 32 + 8 pad

template <int TERMS, int SPLIT_OUT>
__global__ __launch_bounds__(256, 2) void k_gemm(
    const unsigned short* __restrict__ Ahi, const unsigned short* __restrict__ Alo,
    const unsigned short* __restrict__ Bhi, const unsigned short* __restrict__ Blo,
    unsigned short* __restrict__ Chi, unsigned short* __restrict__ Clo,
    int K, int N,
    int aDiv, int aMod, long long aStr,
    int bDiv, int bMod, long long bStr,
    long long cStr) {
  __shared__ unsigned short sA[2][128 * BKP];
  __shared__ unsigned short sB[2][128 * BKP];
  int z = blockIdx.z;
  const unsigned short* A0h = Ahi + (long long)((z / aDiv) % aMod) * aStr;
  const unsigned short* A0l = Alo + (long long)((z / aDiv) % aMod) * aStr;
  const unsigned short* B0h = Bhi + (long long)((z / bDiv) % bMod) * bStr;
  const unsigned short* B0l = Blo + (long long)((z / bDiv) % bMod) * bStr;
  int rT = blockIdx.x * 128, cT = blockIdx.y * 128;
  int tid = threadIdx.x;
  int w = tid >> 6, l = tid & 63, lr = l & 15, lg = l >> 4;
  int wr = w >> 1, wc = w & 1;

  f32x4 acc[4][4];
#pragma unroll
  for (int i = 0; i < 4; i++)
#pragma unroll
    for (int j = 0; j < 4; j++) acc[i][j] = (f32x4){0.f, 0.f, 0.f, 0.f};

  for (int k0 = 0; k0 < K; k0 += 32) {
#pragma unroll
    for (int it = 0; it < 2; it++) {
      int idx = (it * 256 + tid) * 8;
      int r = idx >> 5, c = idx & 31;
      *(s16x8*)&sA[0][r * BKP + c] = *(const s16x8*)(A0h + (size_t)(rT + r) * K + k0 + c);
      *(s16x8*)&sB[0][r * BKP + c] = *(const s16x8*)(B0h + (size_t)(cT + r) * K + k0 + c);
      if (TERMS == 3) {
        *(s16x8*)&sA[1][r * BKP + c] = *(const s16x8*)(A0l + (size_t)(rT + r) * K + k0 + c);
        *(s16x8*)&sB[1][r * BKP + c] = *(const s16x8*)(B0l + (size_t)(cT + r) * K + k0 + c);
      }
    }
    __syncthreads();
    s16x8 ah[4], al[4], bh[4], bl[4];
#pragma unroll
    for (int i = 0; i < 4; i++) {
      ah[i] = *(const s16x8*)&sA[0][(wr * 64 + i * 16 + lr) * BKP + lg * 8];
      if (TERMS == 3) al[i] = *(const s16x8*)&sA[1][(wr * 64 + i * 16 + lr) * BKP + lg * 8];
    }
#pragma unroll
    for (int j = 0; j < 4; j++) {
      bh[j] = *(const s16x8*)&sB[0][(wc * 64 + j * 16 + lr) * BKP + lg * 8];
      if (TERMS == 3) bl[j] = *(const s16x8*)&sB[1][(wc * 64 + j * 16 + lr) * BKP + lg * 8];
    }
#pragma unroll
    for (int i = 0; i < 4; i++)
#pragma unroll
      for (int j = 0; j < 4; j++) {
        acc[i][j] = mfma16(ah[i], bh[j], acc[i][j]);
        if (TERMS == 3) {
          acc[i][j] = mfma16(ah[i], bl[j], acc[i][j]);
          acc[i][j] = mfma16(al[i], bh[j], acc[i][j]);
        }
      }
    __syncthreads();
  }
  long long cOff = (long long)z * cStr;
#pragma unroll
  for (int i = 0; i < 4; i++)
#pragma unroll
    for (int j = 0; j < 4; j++)
#pragma unroll
      for (int r = 0; r < 4; r++) {
        int row = rT + wr * 64 + i * 16 + lg * 4 + r;  // C/D: row=(l>>4)*4+reg
        int col = cT + wc * 64 + j * 16 + lr;          //      col=l&15
        float v = acc[i][j][r];
        unsigned short hb = f2bf(v);
        Chi[cOff + (size_t)row * N + col] = hb;
        if (SPLIT_OUT) Clo[cOff + (size_t)row * N + col] = f2bf(v - bf2f(hb));
      }
}

// ---------------------------------------------------------------------------
// Fused flash attention, round 2:
//  - X tiles double-buffered in LDS, XOR-swizzled rows (512B), 1 barrier/tile
//  - next-tile global loads issued early (reg prefetch), ds_write at tile end
//  - VT read direct from global (L1/L2-resident 32KB tile) in PV
//  - log2-domain online softmax + defer-max (THR=8) + setprio around MFMA
// LDS: 2 bufs x (Xhi 32KB + Xlo 32KB) + P 8x2KB = 147456 B  -> 1 block/CU
#define TT 64
#define ATTN_LDS (2 * 65536 + 8 * 2048)

__global__ __launch_bounds__(512, 2) void k_attn(
    const unsigned short* __restrict__ Yhi, const unsigned short* __restrict__ Ylo,
    const unsigned short* __restrict__ Xhi, const unsigned short* __restrict__ Xlo,
    const unsigned short* __restrict__ VT, float* __restrict__ Out) {
  extern __shared__ char smem[];
  char* sP = smem + 131072;  // [8 waves][16 rows][128B], XOR-swizzled

  // XCD-chunked bijective swizzle: 512 = 8 XCD * 64; 4 consecutive bh per XCD.
  int obid = blockIdx.x;
  int swz = (obid & 7) * 64 + (obid >> 3);
  int qt = swz & 15, bh = swz >> 4;
  int b = bh >> 3;
  int tid = threadIdx.x, w = tid >> 6, l = tid & 63, lr = l & 15, lg = l >> 4;
  const unsigned short* Ybh_h = Yhi + (size_t)bh * (S_N * E_N);
  const unsigned short* Ybh_l = Ylo + (size_t)bh * (S_N * E_N);
  const unsigned short* Xb_h = Xhi + (size_t)b * (S_N * E_N);
  const unsigned short* Xb_l = Xlo + (size_t)b * (S_N * E_N);
  const unsigned short* Vbh = VT + (size_t)bh * (E_N * S_N);
  int qrow = qt * 128 + w * 16;

  // Hoist Y fragments (16 rows x K=256, hi+lo).
  s16x8 yh[8], yl[8];
#pragma unroll
  for (int kc = 0; kc < 8; kc++) {
    yh[kc] = *(const s16x8*)(Ybh_h + (size_t)(qrow + lr) * E_N + kc * 32 + lg * 8);
    yl[kc] = *(const s16x8*)(Ybh_l + (size_t)(qrow + lr) * E_N + kc * 32 + lg * 8);
  }
  f32x4 o[16];
#pragma unroll
  for (int i = 0; i < 16; i++) o[i] = (f32x4){0.f, 0.f, 0.f, 0.f};
  float m2[4], lv[4];
#pragma unroll
  for (int r = 0; r < 4; r++) { m2[r] = -3.0e38f; lv[r] = 0.f; }

  const float C2 = 0.09016844005556021f;  // (1/16) * log2(e)

  // Staging geometry: 4 chunks of 16B per thread per 32KB array.
  int rho[4], cb[4];
#pragma unroll
  for (int it = 0; it < 4; it++) {
    int c = it * 512 + tid;
    rho[it] = c >> 5;          // LDS row (0..63)
    cb[it] = (c & 31) * 16;    // byte-in-row (16B aligned)
  }
  char* sPw = sP + w * 2048;

  // Prologue: load + write tile 0.
  s16x8 pgh[4], pgl[4];
#pragma unroll
  for (int it = 0; it < 4; it++) {
    pgh[it] = *(const s16x8*)(Xb_h + (size_t)rho[it] * E_N + (cb[it] >> 1));
    pgl[it] = *(const s16x8*)(Xb_l + (size_t)rho[it] * E_N + (cb[it] >> 1));
  }
#pragma unroll
  for (int it = 0; it < 4; it++) {
    int a = rho[it] * 512 + (cb[it] ^ ((rho[it] & 7) << 4));
    *(s16x8*)(smem + a) = pgh[it];
    *(s16x8*)(smem + 32768 + a) = pgl[it];
  }

  for (int kt = 0; kt < S_N / TT; kt++) {
    int cur = kt & 1;
    __syncthreads();  // makes buf[cur] visible; prior readers of buf[cur^1] done

    // Prefetch next tile into registers (latency hides under S+PV compute).
    if (kt < 31) {
#pragma unroll
      for (int it = 0; it < 4; it++) {
        pgh[it] = *(const s16x8*)(Xb_h + (size_t)((kt + 1) * TT + rho[it]) * E_N + (cb[it] >> 1));
        pgl[it] = *(const s16x8*)(Xb_l + (size_t)((kt + 1) * TT + rho[it]) * E_N + (cb[it] >> 1));
      }
    }

    const char* bufh = smem + cur * 65536;
    const char* bufl = bufh + 32768;

    // S = Y . X^T (3-term split), raw units.
    f32x4 sc[4];
    __builtin_amdgcn_s_setprio(1);
#pragma unroll
    for (int j = 0; j < 4; j++) {
      f32x4 a = (f32x4){0.f, 0.f, 0.f, 0.f};
#pragma unroll
      for (int kc = 0; kc < 8; kc++) {
        int ad = (j * 16 + lr) * 512 + (((kc * 64) + lg * 16) ^ ((lr & 7) << 4));
        s16x8 xh = *(const s16x8*)(bufh + ad);
        s16x8 xl = *(const s16x8*)(bufl + ad);
        a = mfma16(yh[kc], xh, a);
        a = mfma16(yh[kc], xl, a);
        a = mfma16(yl[kc], xh, a);
      }
      sc[j] = a;
    }
    __builtin_amdgcn_s_setprio(0);

    // Online softmax, log2 domain. Lane holds rows lg*4+r, col lr (+16j).
    float rmax[4];
#pragma unroll
    for (int r = 0; r < 4; r++)
      rmax[r] = fmaxf(fmaxf(sc[0][r], sc[1][r]), fmaxf(sc[2][r], sc[3][r]));
#pragma unroll
    for (int off = 1; off < 16; off <<= 1)
#pragma unroll
      for (int r = 0; r < 4; r++) rmax[r] = fmaxf(rmax[r], __shfl_xor(rmax[r], off, 64));

    float t2[4];
#pragma unroll
    for (int r = 0; r < 4; r++) t2[r] = rmax[r] * C2;

    // Defer-max: skip rescale if per-tile max growth <= 8 (P <= 2^8).
    bool ok = (t2[0] <= m2[0] + 8.f) && (t2[1] <= m2[1] + 8.f) &&
              (t2[2] <= m2[2] + 8.f) && (t2[3] <= m2[3] + 8.f);
    if (!__all(ok)) {
      float fr[4];
#pragma unroll
      for (int r = 0; r < 4; r++) {
        float nm = fmaxf(m2[r], t2[r]);
        fr[r] = exp2f(m2[r] - nm);
        m2[r] = nm;
        lv[r] *= fr[r];
      }
#pragma unroll
      for (int i = 0; i < 16; i++)
#pragma unroll
        for (int r = 0; r < 4; r++) o[i][r] *= fr[r];
    }

    float p[4][4], rs[4];
#pragma unroll
    for (int j = 0; j < 4; j++)
#pragma unroll
      for (int r = 0; r < 4; r++)
        p[j][r] = exp2f(fmaf(sc[j][r], C2, -m2[r]));
#pragma unroll
    for (int r = 0; r < 4; r++) rs[r] = ((p[0][r] + p[1][r]) + (p[2][r] + p[3][r]));
#pragma unroll
    for (int off = 1; off < 16; off <<= 1)
#pragma unroll
      for (int r = 0; r < 4; r++) rs[r] += __shfl_xor(rs[r], off, 64);
#pragma unroll
    for (int r = 0; r < 4; r++) lv[r] += rs[r];

    // P -> LDS bf16 (wave-private, swizzled; write 2-way = free).
#pragma unroll
    for (int j = 0; j < 4; j++)
#pragma unroll
      for (int r = 0; r < 4; r++) {
        int row = lg * 4 + r;
        int off = ((j * 16 + lr) * 2) ^ ((row >> 2) << 5);
        *(unsigned short*)(sPw + row * 128 + off) = f2bf_fast(p[j][r]);
      }

    // O += P . VT   (B-frags direct from global; tile is L1/L2-resident)
    __builtin_amdgcn_s_setprio(1);
#pragma unroll
    for (int tc = 0; tc < 2; tc++) {
      int ap = lr * 128 + (((tc * 64) + lg * 16) ^ ((lr >> 2) << 5));
      s16x8 pa = *(const s16x8*)(sPw + ap);
#pragma unroll
      for (int jf = 0; jf < 16; jf++) {
        s16x8 bv = *(const s16x8*)(Vbh + (size_t)(jf * 16 + lr) * S_N + kt * TT + tc * 32 + lg * 8);
        o[jf] = mfma16(pa, bv, o[jf]);
      }
    }
    __builtin_amdgcn_s_setprio(0);

    // Stage next tile into the other buffer (visible after next barrier).
    if (kt < 31) {
      char* nb = smem + (cur ^ 1) * 65536;
#pragma unroll
      for (int it = 0; it < 4; it++) {
        int a = rho[it] * 512 + (cb[it] ^ ((rho[it] & 7) << 4));
        *(s16x8*)(nb + a) = pgh[it];
        *(s16x8*)(nb + 32768 + a) = pgl[it];
      }
    }
  }

  // Epilogue: normalize rows, head-mean via atomics.
#pragma unroll
  for (int jf = 0; jf < 16; jf++)
#pragma unroll
    for (int r = 0; r < 4; r++) {
      float v = o[jf][r] / lv[r] * 0.125f;
      atomicAdd(&Out[((size_t)b * S_N + qrow + lg * 4 + r) * E_N + jf * 16 + lr], v);
    }
}

// ---------------------------------------------------------------------------
extern "C" void kernel_launch(void* const* d_in, const int* in_sizes, int n_in,
                              void* d_out, int out_size, void* d_ws, size_t ws_size,
                              hipStream_t stream) {
  const float* x = (const float*)d_in[0];
  const float* wq = (const float*)d_in[1];
  const float* wk = (const float*)d_in[2];
  const float* wv = (const float*)d_in[3];
  float* out = (float*)d_out;

  // Workspace layout (bf16 elements; total ~111 MB).
  unsigned short* ws = (unsigned short*)d_ws;
  unsigned short* x_hi = ws;                       // [B,S,E]
  unsigned short* x_lo = x_hi + 2097152;
  unsigned short* wq_hi = x_lo + 2097152;          // [H,E,E]
  unsigned short* wq_lo = wq_hi + 524288;
  unsigned short* wk_hi = wq_lo + 524288;
  unsigned short* wk_lo = wk_hi + 524288;
  unsigned short* wvT = wk_lo + 524288;            // [H,E(f),E(e)]
  unsigned short* mt_hi = wvT + 524288;            // [H,E(e'),E(e)] = Wk.Wq^T
  unsigned short* mt_lo = mt_hi + 524288;
  unsigned short* y_hi = mt_lo + 524288;           // [B,H,S,E]
  unsigned short* y_lo = y_hi + 16777216;
  unsigned short* vt = y_lo + 16777216;            // [B,H,E(f),S(t)]

  hipMemsetAsync(d_out, 0, (size_t)out_size * sizeof(float), stream);

  k_split<<<2048, 256, 0, stream>>>(x, x_hi, x_lo, 524288);
  k_split<<<512, 256, 0, stream>>>(wq, wq_hi, wq_lo, 131072);
  k_split<<<512, 256, 0, stream>>>(wk, wk_hi, wk_lo, 131072);
  k_transpose_wv<<<dim3(8, 8, 8), 256, 0, stream>>>(wv, wvT);

  // MT_h = Wk_h . Wq_h^T   (z = h)
  k_gemm<3, 1><<<dim3(2, 2, 8), 256, 0, stream>>>(
      wk_hi, wk_lo, wq_hi, wq_lo, mt_hi, mt_lo, 256, 256,
      1, 8, 65536LL, 1, 8, 65536LL, 65536LL);
  // Y[b,h] = X_b . MT_h^T   (z = b*H+h)
  k_gemm<3, 1><<<dim3(16, 2, 32), 256, 0, stream>>>(
      x_hi, x_lo, mt_hi, mt_lo, y_hi, y_lo, 256, 256,
      8, 4, 524288LL, 1, 8, 65536LL, 524288LL);
  // VT[b,h] = WvT_h . X_b^T  -> [f][t]  (plain bf16)
  k_gemm<1, 0><<<dim3(2, 16, 32), 256, 0, stream>>>(
      wvT, wvT, x_hi, x_hi, vt, vt, 256, 2048,
      1, 8, 65536LL, 8, 4, 524288LL, 524288LL);

  hipFuncSetAttribute((const void*)k_attn, hipFuncAttributeMaxDynamicSharedMemorySize,
                      ATTN_LDS);
  k_attn<<<dim3(512), 512, ATTN_LDS, stream>>>(y_hi, y_lo, x_hi, x_lo, vt, out);
}

// Round 3
// 476.542 us; speedup vs baseline: 1.8097x; 1.8097x over previous
//
#include <hip/hip_runtime.h>
#include <hip/hip_bf16.h>
#include <cstdint>

// Problem constants (B,S,E,H) = (4, 2048, 256, 8), fp32 in/out.
#define B_N 4
#define S_N 2048
#define E_N 256
#define H_N 8

typedef float f32x4 __attribute__((ext_vector_type(4)));
typedef short s16x8 __attribute__((ext_vector_type(8)));   // 8 bf16 as shorts (4 VGPR)

static __device__ __forceinline__ f32x4 mfma16(s16x8 a, s16x8 b, f32x4 c) {
  return __builtin_amdgcn_mfma_f32_16x16x32_bf16(a, b, c, 0, 0, 0);
}

// fp32 <-> bf16 (RNE) bit ops.
static __device__ __forceinline__ unsigned short f2bf(float f) {
  union { float f; unsigned int u; } v; v.f = f;
  unsigned int r = v.u + 0x7fffu + ((v.u >> 16) & 1u);
  return (unsigned short)(r >> 16);
}
static __device__ __forceinline__ float bf2f(unsigned short s) {
  union { unsigned int u; float f; } v; v.u = ((unsigned int)s) << 16;
  return v.f;
}
static __device__ __forceinline__ unsigned short f2bf_fast(float f) {
  __hip_bfloat16 h = __float2bfloat16(f);
  return *(unsigned short*)&h;
}

// Async global->LDS, 16B per lane. LDS dest: wave-uniform base + lane*16.
static __device__ __forceinline__ void gload16(const void* g, void* l) {
  __builtin_amdgcn_global_load_lds(
      (const __attribute__((address_space(1))) unsigned int*)g,
      (__attribute__((address_space(3))) unsigned int*)l, 16, 0, 0);
}

// ---------------------------------------------------------------------------
// Split fp32 -> bf16 hi + bf16 lo.
__global__ void k_split(const float* __restrict__ src, unsigned short* __restrict__ hi,
                        unsigned short* __restrict__ lo, int n4) {
  int i = blockIdx.x * blockDim.x + threadIdx.x;
  if (i >= n4) return;
  float4 v = ((const float4*)src)[i];
  float f[4] = {v.x, v.y, v.z, v.w};
  unsigned short hh[4], ll[4];
#pragma unroll
  for (int j = 0; j < 4; j++) {
    hh[j] = f2bf(f[j]);
    ll[j] = f2bf(f[j] - bf2f(hh[j]));
  }
  ushort4 h; h.x = hh[0]; h.y = hh[1]; h.z = hh[2]; h.w = hh[3];
  ushort4 l; l.x = ll[0]; l.y = ll[1]; l.z = ll[2]; l.w = ll[3];
  ((ushort4*)hi)[i] = h;
  ((ushort4*)lo)[i] = l;
}

// ---------------------------------------------------------------------------
// WvT[h][f][e] = bf16(Wv[h][e][f])
__global__ void k_transpose_wv(const float* __restrict__ wv, unsigned short* __restrict__ wvT) {
  __shared__ float t[32][33];
  int h = blockIdx.z;
  int e0 = blockIdx.x * 32, f0 = blockIdx.y * 32;
  int tx = threadIdx.x & 31, ty = threadIdx.x >> 5;
  const float* src = wv + ((size_t)h * E_N + e0) * E_N + f0;
#pragma unroll
  for (int r = ty; r < 32; r += 8) t[r][tx] = src[(size_t)r * E_N + tx];
  __syncthreads();
  unsigned short* dst = wvT + ((size_t)h * E_N + f0) * E_N + e0;
#pragma unroll
  for (int r = ty; r < 32; r += 8) dst[(size_t)r * E_N + tx] = f2bf(t[tx][r]);
}

// ---------------------------------------------------------------------------
// bt-GEMM: C[m,n] = sum_k A[m,k]*B[n,k], 128x128 tile, BK=32, 4 waves.
#define BKP 40  // 32 + 8 pad

template <int TERMS, int SPLIT_OUT>
__global__ __launch_bounds__(256, 2) void k_gemm(
    const unsigned short* __restrict__ Ahi, const unsigned short* __restrict__ Alo,
    const unsigned short* __restrict__ Bhi, const unsigned short* __restrict__ Blo,
    unsigned short* __restrict__ Chi, unsigned short* __restrict__ Clo,
    int K, int N,
    int aDiv, int aMod, long long aStr,
    int bDiv, int bMod, long long bStr,
    long long cStr) {
  __shared__ unsigned short sA[2][128 * BKP];
  __shared__ unsigned short sB[2][128 * BKP];
  int z = blockIdx.z;
  const unsigned short* A0h = Ahi + (long long)((z / aDiv) % aMod) * aStr;
  const unsigned short* A0l = Alo + (long long)((z / aDiv) % aMod) * aStr;
  const unsigned short* B0h = Bhi + (long long)((z / bDiv) % bMod) * bStr;
  const unsigned short* B0l = Blo + (long long)((z / bDiv) % bMod) * bStr;
  int rT = blockIdx.x * 128, cT = blockIdx.y * 128;
  int tid = threadIdx.x;
  int w = tid >> 6, l = tid & 63, lr = l & 15, lg = l >> 4;
  int wr = w >> 1, wc = w & 1;

  f32x4 acc[4][4];
#pragma unroll
  for (int i = 0; i < 4; i++)
#pragma unroll
    for (int j = 0; j < 4; j++) acc[i][j] = (f32x4){0.f, 0.f, 0.f, 0.f};

  for (int k0 = 0; k0 < K; k0 += 32) {
#pragma unroll
    for (int it = 0; it < 2; it++) {
      int idx = (it * 256 + tid) * 8;
      int r = idx >> 5, c = idx & 31;
      *(s16x8*)&sA[0][r * BKP + c] = *(const s16x8*)(A0h + (size_t)(rT + r) * K + k0 + c);
      *(s16x8*)&sB[0][r * BKP + c] = *(const s16x8*)(B0h + (size_t)(cT + r) * K + k0 + c);
      if (TERMS == 3) {
        *(s16x8*)&sA[1][r * BKP + c] = *(const s16x8*)(A0l + (size_t)(rT + r) * K + k0 + c);
        *(s16x8*)&sB[1][r * BKP + c] = *(const s16x8*)(B0l + (size_t)(cT + r) * K + k0 + c);
      }
    }
    __syncthreads();
    s16x8 ah[4], al[4], bh[4], bl[4];
#pragma unroll
    for (int i = 0; i < 4; i++) {
      ah[i] = *(const s16x8*)&sA[0][(wr * 64 + i * 16 + lr) * BKP + lg * 8];
      if (TERMS == 3) al[i] = *(const s16x8*)&sA[1][(wr * 64 + i * 16 + lr) * BKP + lg * 8];
    }
#pragma unroll
    for (int j = 0; j < 4; j++) {
      bh[j] = *(const s16x8*)&sB[0][(wc * 64 + j * 16 + lr) * BKP + lg * 8];
      if (TERMS == 3) bl[j] = *(const s16x8*)&sB[1][(wc * 64 + j * 16 + lr) * BKP + lg * 8];
    }
#pragma unroll
    for (int i = 0; i < 4; i++)
#pragma unroll
      for (int j = 0; j < 4; j++) {
        acc[i][j] = mfma16(ah[i], bh[j], acc[i][j]);
        if (TERMS == 3) {
          acc[i][j] = mfma16(ah[i], bl[j], acc[i][j]);
          acc[i][j] = mfma16(al[i], bh[j], acc[i][j]);
        }
      }
    __syncthreads();
  }
  long long cOff = (long long)z * cStr;
#pragma unroll
  for (int i = 0; i < 4; i++)
#pragma unroll
    for (int j = 0; j < 4; j++)
#pragma unroll
      for (int r = 0; r < 4; r++) {
        int row = rT + wr * 64 + i * 16 + lg * 4 + r;  // C/D: row=(l>>4)*4+reg
        int col = cT + wc * 64 + j * 16 + lr;          //      col=l&15
        float v = acc[i][j][r];
        unsigned short hb = f2bf(v);
        Chi[cOff + (size_t)row * N + col] = hb;
        if (SPLIT_OUT) Clo[cOff + (size_t)row * N + col] = f2bf(v - bf2f(hb));
      }
}

// ---------------------------------------------------------------------------
// Fused flash attention, round 3.
// LDS map (bytes):
//   [0,32768)        X hi tile  [64 t][512B], rows XOR-swizzled ^((row&7)<<4)
//   [32768,65536)    X lo tile
//   [65536,131072)   VT double buffer: 2 x [256 f][128B], swizzled
//   [131072,147456)  P: per wave 2KB  [16 r][128B], swizzled
// Staging: global_load_lds w=16 with inverse-swizzled per-lane global source.
// Per tile: B1 -> issue X[kt] (8/wave) + VT[kt+1] (4/wave) -> vmcnt(4) -> B2
//           -> S (96 MFMA) -> softmax -> P -> PV (32 MFMA on VT[kt&1]).
#define TT 64
#define ATTN_LDS 147456

__global__ __launch_bounds__(512, 2) void k_attn(
    const unsigned short* __restrict__ Yhi, const unsigned short* __restrict__ Ylo,
    const unsigned short* __restrict__ Xhi, const unsigned short* __restrict__ Xlo,
    const unsigned short* __restrict__ VT, float* __restrict__ Out) {
  extern __shared__ char smem[];

  // XCD-chunked bijective swizzle: 512 blocks = 8 XCD * 64; same-XCD shares bh.
  int obid = blockIdx.x;
  int swz = (obid & 7) * 64 + (obid >> 3);
  int qt = swz & 15, bh = swz >> 4;
  int b = bh >> 3;
  int tid = threadIdx.x, w = tid >> 6, l = tid & 63, lr = l & 15, lg = l >> 4;
  const unsigned short* Ybh_h = Yhi + (size_t)bh * (S_N * E_N);
  const unsigned short* Ybh_l = Ylo + (size_t)bh * (S_N * E_N);
  const unsigned short* Xb_h = Xhi + (size_t)b * (S_N * E_N);
  const unsigned short* Xb_l = Xlo + (size_t)b * (S_N * E_N);
  const unsigned short* Vbh = VT + (size_t)bh * (E_N * S_N);
  int qrow = qt * 128 + w * 16;

  // Per-lane staging descriptors (inverse-swizzled global element offsets).
  int xoff[4], voff[4], ldsb[4];
#pragma unroll
  for (int i = 0; i < 4; i++) {
    int c = (w * 4 + i) * 64 + l;
    ldsb[i] = (w * 4 + i) * 1024;  // wave-uniform LDS base for this instr
    int rx = c >> 5, cbx = (c & 31) * 16;
    xoff[i] = rx * E_N + (((cbx) ^ ((rx & 7) << 4)) >> 1);
    int rv = c >> 3, cbv = (c & 7) * 16;
    voff[i] = rv * S_N + (((cbv) ^ ((rv & 7) << 4)) >> 1);
  }
  char* sPw = smem + 131072 + w * 2048;

  // Hoist Y fragments (16 rows x K=256, hi+lo) into registers.
  s16x8 yh[8], yl[8];
#pragma unroll
  for (int kc = 0; kc < 8; kc++) {
    yh[kc] = *(const s16x8*)(Ybh_h + (size_t)(qrow + lr) * E_N + kc * 32 + lg * 8);
    yl[kc] = *(const s16x8*)(Ybh_l + (size_t)(qrow + lr) * E_N + kc * 32 + lg * 8);
  }
  f32x4 o[16];
#pragma unroll
  for (int i = 0; i < 16; i++) o[i] = (f32x4){0.f, 0.f, 0.f, 0.f};
  float m2[4], lv[4];
#pragma unroll
  for (int r = 0; r < 4; r++) { m2[r] = -3.0e38f; lv[r] = 0.f; }

  const float C2 = 0.09016844005556021f;  // (1/16) * log2(e)

  // Prologue: issue VT[0] prefetch (lands before first B2's vmcnt).
#pragma unroll
  for (int i = 0; i < 4; i++)
    gload16(Vbh + voff[i], smem + 65536 + ldsb[i]);

  for (int kt = 0; kt < S_N / TT; kt++) {
    __builtin_amdgcn_s_barrier();  // B1: all waves done with X[kt-1], VT[kt-1]

    // Issue X[kt] (hi+lo) and VT[kt+1] staging.
#pragma unroll
    for (int i = 0; i < 4; i++) {
      gload16(Xb_h + (size_t)kt * (TT * E_N) + xoff[i], smem + ldsb[i]);
      gload16(Xb_l + (size_t)kt * (TT * E_N) + xoff[i], smem + 32768 + ldsb[i]);
    }
    if (kt < 31) {
#pragma unroll
      for (int i = 0; i < 4; i++)
        gload16(Vbh + (kt + 1) * TT + voff[i],
                smem + 65536 + ((kt + 1) & 1) * 32768 + ldsb[i]);
      asm volatile("s_waitcnt vmcnt(4)" ::: "memory");  // X[kt]+VT[kt] done
    } else {
      asm volatile("s_waitcnt vmcnt(0)" ::: "memory");
    }
    __builtin_amdgcn_s_barrier();  // B2: staged data visible to all waves

    const char* bufh = smem;
    const char* bufl = smem + 32768;
    const char* vbuf = smem + 65536 + (kt & 1) * 32768;

    // S = Y . X^T (3-term split), raw units.
    f32x4 sc[4];
    __builtin_amdgcn_s_setprio(1);
#pragma unroll
    for (int j = 0; j < 4; j++) {
      f32x4 a = (f32x4){0.f, 0.f, 0.f, 0.f};
#pragma unroll
      for (int kc = 0; kc < 8; kc++) {
        int ad = (j * 16 + lr) * 512 + ((kc * 64 + lg * 16) ^ ((lr & 7) << 4));
        s16x8 xh = *(const s16x8*)(bufh + ad);
        s16x8 xl = *(const s16x8*)(bufl + ad);
        a = mfma16(yh[kc], xh, a);
        a = mfma16(yh[kc], xl, a);
        a = mfma16(yl[kc], xh, a);
      }
      sc[j] = a;
    }
    __builtin_amdgcn_s_setprio(0);

    // Online softmax, log2 domain. Lane holds rows lg*4+r, col lr (+16j).
    float rmax[4];
#pragma unroll
    for (int r = 0; r < 4; r++)
      rmax[r] = fmaxf(fmaxf(sc[0][r], sc[1][r]), fmaxf(sc[2][r], sc[3][r]));
#pragma unroll
    for (int off = 1; off < 16; off <<= 1)
#pragma unroll
      for (int r = 0; r < 4; r++) rmax[r] = fmaxf(rmax[r], __shfl_xor(rmax[r], off, 64));

    float t2[4];
#pragma unroll
    for (int r = 0; r < 4; r++) t2[r] = rmax[r] * C2;

    // Defer-max: skip rescale if per-tile max growth <= 8 (P <= 2^8).
    bool ok = (t2[0] <= m2[0] + 8.f) && (t2[1] <= m2[1] + 8.f) &&
              (t2[2] <= m2[2] + 8.f) && (t2[3] <= m2[3] + 8.f);
    if (!__all(ok)) {
      float fr[4];
#pragma unroll
      for (int r = 0; r < 4; r++) {
        float nm = fmaxf(m2[r], t2[r]);
        fr[r] = exp2f(m2[r] - nm);
        m2[r] = nm;
        lv[r] *= fr[r];
      }
#pragma unroll
      for (int i = 0; i < 16; i++)
#pragma unroll
        for (int r = 0; r < 4; r++) o[i][r] *= fr[r];
    }

    float p[4][4], rs[4];
#pragma unroll
    for (int j = 0; j < 4; j++)
#pragma unroll
      for (int r = 0; r < 4; r++)
        p[j][r] = exp2f(fmaf(sc[j][r], C2, -m2[r]));
#pragma unroll
    for (int r = 0; r < 4; r++) rs[r] = ((p[0][r] + p[1][r]) + (p[2][r] + p[3][r]));
#pragma unroll
    for (int off = 1; off < 16; off <<= 1)
#pragma unroll
      for (int r = 0; r < 4; r++) rs[r] += __shfl_xor(rs[r], off, 64);
#pragma unroll
    for (int r = 0; r < 4; r++) lv[r] += rs[r];

    // P -> LDS bf16 (wave-private, swizzled).
#pragma unroll
    for (int j = 0; j < 4; j++)
#pragma unroll
      for (int r = 0; r < 4; r++) {
        int row = lg * 4 + r;
        int off = ((j * 16 + lr) * 2) ^ ((row & 7) << 4);
        *(unsigned short*)(sPw + row * 128 + off) = f2bf_fast(p[j][r]);
      }

    // O += P . VT  (bt-form; VT from double-buffered LDS)
    __builtin_amdgcn_s_setprio(1);
#pragma unroll
    for (int tc = 0; tc < 2; tc++) {
      int ap = lr * 128 + ((tc * 64 + lg * 16) ^ ((lr & 7) << 4));
      s16x8 pa = *(const s16x8*)(sPw + ap);
#pragma unroll
      for (int jf = 0; jf < 16; jf++) {
        int ad = (jf * 16 + lr) * 128 + ((tc * 64 + lg * 16) ^ ((lr & 7) << 4));
        s16x8 bv = *(const s16x8*)(vbuf + ad);
        o[jf] = mfma16(pa, bv, o[jf]);
      }
    }
    __builtin_amdgcn_s_setprio(0);
  }

  // Epilogue: normalize rows, head-mean via atomics.
#pragma unroll
  for (int jf = 0; jf < 16; jf++)
#pragma unroll
    for (int r = 0; r < 4; r++) {
      float v = o[jf][r] / lv[r] * 0.125f;
      atomicAdd(&Out[((size_t)b * S_N + qrow + lg * 4 + r) * E_N + jf * 16 + lr], v);
    }
}

// ---------------------------------------------------------------------------
extern "C" void kernel_launch(void* const* d_in, const int* in_sizes, int n_in,
                              void* d_out, int out_size, void* d_ws, size_t ws_size,
                              hipStream_t stream) {
  const float* x = (const float*)d_in[0];
  const float* wq = (const float*)d_in[1];
  const float* wk = (const float*)d_in[2];
  const float* wv = (const float*)d_in[3];
  float* out = (float*)d_out;

  unsigned short* ws = (unsigned short*)d_ws;
  unsigned short* x_hi = ws;                       // [B,S,E]
  unsigned short* x_lo = x_hi + 2097152;
  unsigned short* wq_hi = x_lo + 2097152;          // [H,E,E]
  unsigned short* wq_lo = wq_hi + 524288;
  unsigned short* wk_hi = wq_lo + 524288;
  unsigned short* wk_lo = wk_hi + 524288;
  unsigned short* wvT = wk_lo + 524288;            // [H,E(f),E(e)]
  unsigned short* mt_hi = wvT + 524288;            // [H,E,E] = Wk.Wq^T
  unsigned short* mt_lo = mt_hi + 524288;
  unsigned short* y_hi = mt_lo + 524288;           // [B,H,S,E]
  unsigned short* y_lo = y_hi + 16777216;
  unsigned short* vt = y_lo + 16777216;            // [B,H,E(f),S(t)]

  hipMemsetAsync(d_out, 0, (size_t)out_size * sizeof(float), stream);

  k_split<<<2048, 256, 0, stream>>>(x, x_hi, x_lo, 524288);
  k_split<<<512, 256, 0, stream>>>(wq, wq_hi, wq_lo, 131072);
  k_split<<<512, 256, 0, stream>>>(wk, wk_hi, wk_lo, 131072);
  k_transpose_wv<<<dim3(8, 8, 8), 256, 0, stream>>>(wv, wvT);

  // MT_h = Wk_h . Wq_h^T
  k_gemm<3, 1><<<dim3(2, 2, 8), 256, 0, stream>>>(
      wk_hi, wk_lo, wq_hi, wq_lo, mt_hi, mt_lo, 256, 256,
      1, 8, 65536LL, 1, 8, 65536LL, 65536LL);
  // Y[b,h] = X_b . MT_h^T
  k_gemm<3, 1><<<dim3(16, 2, 32), 256, 0, stream>>>(
      x_hi, x_lo, mt_hi, mt_lo, y_hi, y_lo, 256, 256,
      8, 4, 524288LL, 1, 8, 65536LL, 524288LL);
  // VT[b,h] = WvT_h . X_b^T
  k_gemm<1, 0><<<dim3(2, 16, 32), 256, 0, stream>>>(
      wvT, wvT, x_hi, x_hi, vt, vt, 256, 2048,
      1, 8, 65536LL, 8, 4, 524288LL, 524288LL);

  hipFuncSetAttribute((const void*)k_attn, hipFuncAttributeMaxDynamicSharedMemorySize,
                      ATTN_LDS);
  k_attn<<<dim3(512), 512, ATTN_LDS, stream>>>(y_hi, y_lo, x_hi, x_lo, vt, out);
}